// Round 15
// baseline (367.080 us; speedup 1.0000x reference)
//
#include <hip/hip_runtime.h>
#include <hip/hip_bf16.h>
#include <cstdint>

// ---------------------------------------------------------------------------
// Model: h=relu(x@W1+b1); h=AGNN(h,beta=1); h=AGNN(h,beta2); h=relu(h@W2+b2);
//        out = concat(segmax(h,batch), segmean(h,batch)) @ W3 + b3
// N=30000, E=480000, F_IN=1280, H=512, H2=256, G=64, C=10
// bf16 rows after GEMM1. GEMM cost model (r12/r13/r14 A/B): duration ~
// block x K-step count (fixed barrier/drain cost per step), NOT traffic.
// => maximize tile: BM=256 x BN=256, 8 waves (2m x 4n), wave tile 128x64,
// acc[8][4], 2-phase schedule, 64KB dbuf LDS, plain 2D grid (L3 absorbs the
// y-sibling A re-read; r13 FETCH=155MB). GEMM1 epilogue emits per-row sumsq
// partials; XOR-swizzled LDS; AGNN fixed-shift softmax + 2-edge ILP + DPP;
// CSR via memset+scan-fold; fused pool+final. 12 launches total.
// ---------------------------------------------------------------------------

typedef __attribute__((ext_vector_type(8))) short bf16x8;
typedef __attribute__((ext_vector_type(4))) float f32x4;
typedef __attribute__((ext_vector_type(8))) unsigned short ushort8;
typedef __attribute__((ext_vector_type(4))) unsigned short ushort4v;
typedef __attribute__((ext_vector_type(4))) unsigned int uint4v;

__device__ inline unsigned short f2bf(float f) {
    unsigned int u = __float_as_uint(f);
    u += 0x7FFFu + ((u >> 16) & 1u);   // RNE
    return (unsigned short)(u >> 16);
}

__device__ __forceinline__ float bf2f(unsigned short u) {
    return __uint_as_float(((unsigned int)u) << 16);
}

// packed f32x2 -> bf16x2 (RNE), single HW instruction on gfx950
__device__ __forceinline__ unsigned int cvtpk(float lo, float hi) {
    unsigned int r;
    asm("v_cvt_pk_bf16_f32 %0, %1, %2" : "=v"(r) : "v"(lo), "v"(hi));
    return r;
}

__device__ __forceinline__ void gload_lds16(const void* g, void* l) {
    __builtin_amdgcn_global_load_lds(
        (const __attribute__((address_space(1))) void*)g,
        (__attribute__((address_space(3))) void*)l, 16, 0, 0);
}

// ---- wave64 sum via DPP (VALU pipe). Result uniform across the wave. ------
__device__ __forceinline__ float wave_sum_dpp(float p) {
    int t;
    t = __builtin_amdgcn_update_dpp(0, __float_as_int(p), 0xB1, 0xf, 0xf, true);  // quad_perm [1,0,3,2]
    p += __int_as_float(t);
    t = __builtin_amdgcn_update_dpp(0, __float_as_int(p), 0x4E, 0xf, 0xf, true);  // quad_perm [2,3,0,1]
    p += __int_as_float(t);
    t = __builtin_amdgcn_update_dpp(0, __float_as_int(p), 0x141, 0xf, 0xf, true); // row_half_mirror
    p += __int_as_float(t);
    t = __builtin_amdgcn_update_dpp(0, __float_as_int(p), 0x140, 0xf, 0xf, true); // row_mirror
    p += __int_as_float(t);
    t = __builtin_amdgcn_update_dpp(0, __float_as_int(p), 0x142, 0xf, 0xf, true); // row_bcast15
    p += __int_as_float(t);
    t = __builtin_amdgcn_update_dpp(0, __float_as_int(p), 0x143, 0xf, 0xf, true); // row_bcast31
    p += __int_as_float(t);
    return __int_as_float(__builtin_amdgcn_readlane(__float_as_int(p), 63));
}

// ---- sum across each 16-lane group (DPP row); all 16 lanes get the sum ----
__device__ __forceinline__ float row16_sum_dpp(float p) {
    int t;
    t = __builtin_amdgcn_update_dpp(0, __float_as_int(p), 0xB1, 0xf, 0xf, true);  // quad_perm xor1
    p += __int_as_float(t);
    t = __builtin_amdgcn_update_dpp(0, __float_as_int(p), 0x4E, 0xf, 0xf, true);  // quad_perm xor2
    p += __int_as_float(t);
    t = __builtin_amdgcn_update_dpp(0, __float_as_int(p), 0x141, 0xf, 0xf, true); // row_half_mirror
    p += __int_as_float(t);
    t = __builtin_amdgcn_update_dpp(0, __float_as_int(p), 0x140, 0xf, 0xf, true); // row_mirror
    p += __int_as_float(t);
    return p;
}

// ---- merged tiled transpose: both weights in one launch -------------------
__global__ __launch_bounds__(256) void k_transpose_both(
    const float* __restrict__ W1, unsigned short* __restrict__ W1T,
    int K1, int N1, int nt1,
    const float* __restrict__ W2, unsigned short* __restrict__ W2T,
    int K2, int N2) {
    __shared__ unsigned short tb[32][33];
    int id = blockIdx.x;
    const float* W; unsigned short* Wt; int K, N, bx, by;
    if (id < nt1) {
        W = W1; Wt = W1T; K = K1; N = N1;
        int nx = K1 / 32; bx = id % nx; by = id / nx;
    } else {
        id -= nt1;
        W = W2; Wt = W2T; K = K2; N = N2;
        int nx = K2 / 32; bx = id % nx; by = id / nx;
    }
    int k0 = bx * 32, n0 = by * 32;
    int tr = threadIdx.x >> 3;          // 0..31
    int tc = (threadIdx.x & 7) * 4;     // 0,4,...,28
    float4 v = *(const float4*)(W + (long)(k0 + tr) * N + n0 + tc);
    tb[tr][tc + 0] = f2bf(v.x); tb[tr][tc + 1] = f2bf(v.y);
    tb[tr][tc + 2] = f2bf(v.z); tb[tr][tc + 3] = f2bf(v.w);
    __syncthreads();
    ushort4v o = { tb[tc + 0][tr], tb[tc + 1][tr], tb[tc + 2][tr], tb[tc + 3][tr] };
    *(ushort4v*)(Wt + (long)(n0 + tr) * K + k0 + tc) = o;
}

// ---- MFMA GEMM: C[M][N] = relu(A[M][K] @ Bt[N][K]^T + bias) ---------------
// Proven 2-phase schedule, maximal tile: block BM x BN (256x256), 512
// threads = 8 waves (2m x 4n), wave tile (BM/2) x (BN/4) = 128x64,
// acc[MF=8][NF=4], BK=32, double-buffered LDS (64 KB), ONE __syncthreads
// per K-step; next-tile loads issued before the MFMAs. Minimizes
// block x K-step count (the empirically-dominant fixed cost, r12-r14).
// PSUM_EN: epilogue reduces per-row sum of squares via 16-lane DPP groups;
// psum[row*SLOTS + blockIdx.y*4 + wn]; SLOTS = (NOUT/BN)*4.
// LDS rows 64B; 16B granule g of row r at slot g ^ ((r>>1)&3) (conflict-free,
// both sides). AF32: A f32 in global, reg-staged in-step + packed to bf16
// (BM/128 row-passes per thread).
template <int BM, int K, int BN, int NOUT, bool AF32, bool OUTBF16, bool PSUM_EN>
__global__ __launch_bounds__(512, 2) void k_gemm_bias_relu(
    const void* __restrict__ Av, const unsigned short* __restrict__ Bt,
    const float* __restrict__ bias, void* __restrict__ Cv,
    float* __restrict__ psum, int M) {
    constexpr int NSTEP = K / 32;
    constexpr int MF = BM / 32;          // m-frags per wave (2 m-waves)
    constexpr int NF = BN / 64;          // n-frags per wave (4 n-waves)
    constexpr int AP = BM / 128;         // A f32 staging passes
    constexpr int SLOTS = (NOUT / BN) * 4;
    __shared__ unsigned short As[2][BM * 32];
    __shared__ unsigned short Bs[2][BN * 32];
    int tid = threadIdx.x;
    int w = tid >> 6, l = tid & 63;
    int wm = w >> 2, wn = w & 3;
    int mBase = blockIdx.x * BM;
    int nBase = blockIdx.y * BN;

    const float* Af = (const float*)Av;
    const unsigned short* Ab = (const unsigned short*)Av;

    // AF32 reg-staging: per pass p, thread owns 8 consecutive f32 of row
    // p*128 + (tid>>2). Swizzle slot independent of p (p*128 ≡ 0 mod 4 rows).
    int arow = tid >> 2;                          // 0..127 (pass-local)
    int aslot = (tid & 3) ^ ((arow >> 1) & 3);    // swizzled 16B slot
    const float* aptrs[AP];
#pragma unroll
    for (int p = 0; p < AP; ++p) {
        long gr = mBase + p * 128 + arow; if (gr >= M) gr = M - 1;
        aptrs[p] = Af + gr * K + (tid & 3) * 8;
    }

    auto stageB = [&](int bb, int k0) {
#pragma unroll
        for (int o = 0; o < BN / 128; ++o) {
            int rbase = (w * (BN / 128) + o) * 16;           // wave-uniform
            int row = rbase + (l >> 2);                      // local B row
            int gsrc = (l & 3) ^ ((row >> 1) & 3);           // pre-swizzled src
            gload_lds16(Bt + (long)(nBase + row) * K + k0 + gsrc * 8,
                        &Bs[bb][rbase * 32]);
        }
    };
    auto stageAbf = [&](int bb, int k0) {
#pragma unroll
        for (int o = 0; o < BM / 128; ++o) {
            int rbase = (w * (BM / 128) + o) * 16;
            int row = rbase + (l >> 2);
            int gsrc = (l & 3) ^ ((row >> 1) & 3);
            long gr = mBase + row; if (gr >= M) gr = M - 1;
            gload_lds16(Ab + gr * K + k0 + gsrc * 8, &As[bb][rbase * 32]);
        }
    };

    f32x4 acc[MF][NF] = {};

    // ---- prologue: stage k-tile 0 into buffer 0 ---------------------------
    stageB(0, 0);
    if constexpr (AF32) {
#pragma unroll
        for (int p = 0; p < AP; ++p) {
            float4 z0 = *(const float4*)(aptrs[p]);
            float4 z1 = *(const float4*)(aptrs[p] + 4);
            uint4v pk = { cvtpk(z0.x, z0.y), cvtpk(z0.z, z0.w),
                          cvtpk(z1.x, z1.y), cvtpk(z1.z, z1.w) };
            *(uint4v*)(&As[0][(p * 128 + arow) * 32 + aslot * 8]) = pk;
        }
    } else {
        stageAbf(0, 0);
    }
    __syncthreads();

    int s = 0;
    for (int step = 0; step < NSTEP; ++step, s ^= 1) {
        int nk = (step + 1) * 32;
        float4 f0[AP], f1[AP];
        if (nk < K) {                      // issue next-tile loads FIRST
            stageB(s ^ 1, nk);
            if constexpr (AF32) {
#pragma unroll
                for (int p = 0; p < AP; ++p) {
                    f0[p] = *(const float4*)(aptrs[p] + nk);
                    f1[p] = *(const float4*)(aptrs[p] + nk + 4);
                }
            } else {
                stageAbf(s ^ 1, nk);
            }
        }
        // ---- compute current buffer (swizzled reads) ----------------------
        bf16x8 af[MF];
#pragma unroll
        for (int m = 0; m < MF; ++m) {
            int ra = wm * (BM / 2) + m * 16 + (l & 15);
            int g = (l >> 4) ^ ((ra >> 1) & 3);
            af[m] = *(const bf16x8*)(&As[s][ra * 32 + g * 8]);
        }
#pragma unroll
        for (int n = 0; n < NF; ++n) {
            int rb = wn * (BN / 4) + n * 16 + (l & 15);
            int g = (l >> 4) ^ ((rb >> 1) & 3);
            bf16x8 bfr = *(const bf16x8*)(&Bs[s][rb * 32 + g * 8]);
#pragma unroll
            for (int m = 0; m < MF; ++m)
                acc[m][n] = __builtin_amdgcn_mfma_f32_16x16x32_bf16(
                    af[m], bfr, acc[m][n], 0, 0, 0);
        }
        if constexpr (AF32) {
            if (nk < K) {                    // write next A after MFMAs
#pragma unroll
                for (int p = 0; p < AP; ++p) {
                    uint4v pk = { cvtpk(f0[p].x, f0[p].y), cvtpk(f0[p].z, f0[p].w),
                                  cvtpk(f1[p].x, f1[p].y), cvtpk(f1[p].z, f1[p].w) };
                    *(uint4v*)(&As[s ^ 1][(p * 128 + arow) * 32 + aslot * 8]) = pk;
                }
            }
        }
        __syncthreads();
    }

    // ---- epilogue: row=(l>>4)*4+r, col=l&15 (HW-verified) -----------------
    float bv[NF];
#pragma unroll
    for (int n = 0; n < NF; ++n)
        bv[n] = bias[nBase + wn * (BN / 4) + n * 16 + (l & 15)];
#pragma unroll
    for (int m = 0; m < MF; ++m) {
#pragma unroll
        for (int r = 0; r < 4; ++r) {
            int row = mBase + wm * (BM / 2) + m * 16 + (l >> 4) * 4 + r;
            float sq = 0.f;
#pragma unroll
            for (int n = 0; n < NF; ++n) {
                float v = fmaxf(acc[m][n][r] + bv[n], 0.f);
                sq += v * v;
                if (row < M) {
                    int colg = nBase + wn * (BN / 4) + n * 16 + (l & 15);
                    if constexpr (OUTBF16)
                        ((unsigned short*)Cv)[(long)row * NOUT + colg] = f2bf(v);
                    else
                        ((float*)Cv)[(long)row * NOUT + colg] = v;
                }
            }
            if constexpr (PSUM_EN) {
                sq = row16_sum_dpp(sq);      // sum over this wave's cols
                if ((l & 15) == 0 && row < M)
                    psum[(long)row * SLOTS + blockIdx.y * 4 + wn] = sq;
            }
        }
    }
}

// ---- finish: invn[i] = rsqrt(sum of SLOTS psum entries) -------------------
template <int SLOTS>
__global__ void k_rsqrt(const float* __restrict__ psum,
                        float* __restrict__ invn, int n) {
    int i = blockIdx.x * 256 + threadIdx.x;
    if (i >= n) return;
    const float* p = psum + (long)i * SLOTS;
    float s = 0.f;
#pragma unroll
    for (int j = 0; j < SLOTS; j += 4) {
        float4 a = *(const float4*)(p + j);
        s += (a.x + a.y) + (a.z + a.w);
    }
    invn[i] = 1.f / fmaxf(sqrtf(s), 1e-12f);
}

// ---- CSR build ------------------------------------------------------------
__global__ void k_csr_count(const int* __restrict__ ei, int* __restrict__ cnt, int E) {
    int e = blockIdx.x * blockDim.x + threadIdx.x;
    if (e < E) atomicAdd(&cnt[ei[E + e]], 1);   // dst row
}

// phase 1: per-1024-chunk exclusive scan of (cnt[i]+1) + chunk totals.
// The +1 is the self-loop (replaces a separate init kernel).
__global__ __launch_bounds__(1024) void k_scan1(const int* __restrict__ cnt,
                                                int* __restrict__ rowp,
                                                int* __restrict__ bsum, int n) {
    __shared__ int wsum[16];
    int b = blockIdx.x, t = threadIdx.x, lane = t & 63, w = t >> 6;
    int i = b * 1024 + t;
    int v = (i < n) ? cnt[i] + 1 : 0;
    int x = v;
#pragma unroll
    for (int off = 1; off < 64; off <<= 1) {
        int y = __shfl_up(x, off, 64);
        if (lane >= off) x += y;
    }
    if (lane == 63) wsum[w] = x;
    __syncthreads();
    if (t < 16) {
        int s = wsum[t];
#pragma unroll
        for (int off = 1; off < 16; off <<= 1) {
            int y = __shfl_up(s, off, 64);
            if (t >= off) s += y;
        }
        wsum[t] = s;
    }
    __syncthreads();
    int wo = w ? wsum[w - 1] : 0;
    if (i < n) rowp[i] = wo + x - v;            // chunk-local exclusive
    if (t == 0) bsum[b] = wsum[15];             // chunk total
}

// phase 2+3 fused: every block redundantly wave-scans the <=64 chunk totals,
// then adds its chunk offset; rowp[n] = grand total.
__global__ __launch_bounds__(1024) void k_scan23(const int* __restrict__ bsum,
                                                 int* __restrict__ rowp, int n, int nb) {
    __shared__ int off[65];
    int t = threadIdx.x;
    if (t < 64) {
        int v = (t < nb) ? bsum[t] : 0;
        int x = v;
#pragma unroll
        for (int o = 1; o < 64; o <<= 1) {
            int y = __shfl_up(x, o, 64);
            if (t >= o) x += y;
        }
        off[t] = x - v;                    // exclusive
        if (t == nb - 1) off[64] = x;      // total
    }
    __syncthreads();
    int i = blockIdx.x * 1024 + t;
    if (i < n) rowp[i] += off[i >> 10];
    else if (i == n) rowp[n] = off[64];
}

__global__ void k_csr_fill(const int* __restrict__ ei, const int* __restrict__ rowp,
                           int* __restrict__ fill, int* __restrict__ col, int E, int n) {
    int idx = blockIdx.x * blockDim.x + threadIdx.x;
    if (idx < E) {
        int d = ei[E + idx];
        int s = ei[idx];
        int pos = atomicAdd(&fill[d], 1);
        col[rowp[d] + pos] = s;
    } else if (idx < E + n) {
        int nd = idx - E;
        int pos = atomicAdd(&fill[nd], 1);
        col[rowp[nd] + pos] = nd;   // self loop
    }
}

// ---- AGNN propagation: bf16 rows, one wave per dst, single-pass -----------
// Fixed-shift softmax: alpha = beta*cos(theta) bounded by |beta|*(1+eps), so
// exp(alpha - 1.0625|beta|) never overflows; shift invariance => exact.
// 2-edge interleave + 4-deep row prefetch + DPP reduce.
__global__ __launch_bounds__(256) void k_agnn(
    const unsigned short* __restrict__ h, const float* __restrict__ invn,
    const int* __restrict__ rowp, const int* __restrict__ col,
    const float* __restrict__ beta_ptr, unsigned short* __restrict__ out,
    float* __restrict__ invn_out, int nNodes) {
    int dst = blockIdx.x * 4 + (threadIdx.x >> 6);
    int lane = threadIdx.x & 63;
    if (dst >= nNodes) return;
    float beta = beta_ptr ? beta_ptr[0] : 1.0f;
    ushort8 hdv = *(const ushort8*)(h + (long)dst * 512 + lane * 8);
    float hd[8];
#pragma unroll
    for (int e = 0; e < 8; ++e) hd[e] = bf2f(hdv[e]);
    float coef = beta * invn[dst];
    float mshift = fabsf(beta) * 1.0625f;   // >= max possible alpha
    int s0 = rowp[dst], s1 = rowp[dst + 1];

    float ssum = 0.f;
    float accE[8] = {0.f, 0.f, 0.f, 0.f, 0.f, 0.f, 0.f, 0.f};
    float accO[8] = {0.f, 0.f, 0.f, 0.f, 0.f, 0.f, 0.f, 0.f};

    for (int base = s0; base < s1; base += 64) {
        int cnt = min(s1 - base, 64);
        int gi = base + lane; if (gi >= s1) gi = s1 - 1;
        int idxl = col[gi];              // batch of up to 64 edge indices
        float vinl = invn[idxl];         // batch of src inv-norms
        ushort8 r0 = {}, r1 = {}, r2 = {}, r3 = {};
        r0 = *(const ushort8*)(h + (long)__builtin_amdgcn_readlane(idxl, 0) * 512 + lane * 8);
        if (cnt > 1) r1 = *(const ushort8*)(h + (long)__builtin_amdgcn_readlane(idxl, 1) * 512 + lane * 8);
        if (cnt > 2) r2 = *(const ushort8*)(h + (long)__builtin_amdgcn_readlane(idxl, 2) * 512 + lane * 8);
        if (cnt > 3) r3 = *(const ushort8*)(h + (long)__builtin_amdgcn_readlane(idxl, 3) * 512 + lane * 8);
        int j = 0;
        for (; j + 1 < cnt; j += 2) {
            ushort8 c0 = r0, c1 = r1;
            r0 = r2; r1 = r3;
            if (j + 4 < cnt) r2 = *(const ushort8*)(h + (long)__builtin_amdgcn_readlane(idxl, j + 4) * 512 + lane * 8);
            if (j + 5 < cnt) r3 = *(const ushort8*)(h + (long)__builtin_amdgcn_readlane(idxl, j + 5) * 512 + lane * 8);
            float a0[8], a1[8];
#pragma unroll
            for (int e = 0; e < 8; ++e) { a0[e] = bf2f(c0[e]); a1[e] = bf2f(c1[e]); }
            float p0 = a0[0] * hd[0] + a0[1] * hd[1] + a0[2] * hd[2] + a0[3] * hd[3] +
                       a0[4] * hd[4] + a0[5] * hd[5] + a0[6] * hd[6] + a0[7] * hd[7];
            float p1 = a1[0] * hd[0] + a1[1] * hd[1] + a1[2] * hd[2] + a1[3] * hd[3] +
                       a1[4] * hd[4] + a1[5] * hd[5] + a1[6] * hd[6] + a1[7] * hd[7];
            p0 = wave_sum_dpp(p0);       // two independent chains interleave
            p1 = wave_sum_dpp(p1);
            float al0 = coef * __int_as_float(__builtin_amdgcn_readlane(__float_as_int(vinl), j)) * p0;
            float al1 = coef * __int_as_float(__builtin_amdgcn_readlane(__float_as_int(vinl), j + 1)) * p1;
            float w0 = __expf(al0 - mshift);
            float w1 = __expf(al1 - mshift);
            ssum += w0 + w1;
#pragma unroll
            for (int e = 0; e < 8; ++e) { accE[e] += w0 * a0[e]; accO[e] += w1 * a1[e]; }
        }
        if (j < cnt) {                   // odd tail
            float a0[8];
#pragma unroll
            for (int e = 0; e < 8; ++e) a0[e] = bf2f(r0[e]);
            float p0 = a0[0] * hd[0] + a0[1] * hd[1] + a0[2] * hd[2] + a0[3] * hd[3] +
                       a0[4] * hd[4] + a0[5] * hd[5] + a0[6] * hd[6] + a0[7] * hd[7];
            p0 = wave_sum_dpp(p0);
            float al0 = coef * __int_as_float(__builtin_amdgcn_readlane(__float_as_int(vinl), j)) * p0;
            float w0 = __expf(al0 - mshift);
            ssum += w0;
#pragma unroll
            for (int e = 0; e < 8; ++e) accE[e] += w0 * a0[e];
        }
    }
    float inv_s = 1.f / ssum;
    float acc[8];
#pragma unroll
    for (int e = 0; e < 8; ++e) acc[e] = (accE[e] + accO[e]) * inv_s;

    uint4v o = { cvtpk(acc[0], acc[1]), cvtpk(acc[2], acc[3]),
                 cvtpk(acc[4], acc[5]), cvtpk(acc[6], acc[7]) };
    *(uint4v*)(out + (long)dst * 512 + lane * 8) = o;

    if (invn_out) {                      // fused output norm (feeds next prop)
        float s = 0.f;
#pragma unroll
        for (int e = 0; e < 8; ++e) s += acc[e] * acc[e];
        s = wave_sum_dpp(s);
        if (lane == 0) invn_out[dst] = 1.f / fmaxf(sqrtf(s), 1e-12f);
    }
}

// ---- fused per-graph pool (max/mean, bf16 in) + final linear --------------
__global__ __launch_bounds__(256) void k_pool_final(
    const unsigned short* __restrict__ h3, const int* __restrict__ batch,
    const float* __restrict__ W3, const float* __restrict__ b3,
    float* __restrict__ out, int n, int C) {
    __shared__ int se[2];
    __shared__ float wpart[4];
    int g = blockIdx.x;
    int t = threadIdx.x;
    if (t < 2) {                         // binary search graph boundaries
        int tgt = g + t;
        int lo = 0, hi = n;
        while (lo < hi) {
            int mid = (lo + hi) >> 1;
            if (batch[mid] < tgt) lo = mid + 1; else hi = mid;
        }
        se[t] = lo;
    }
    __syncthreads();
    int s = se[0], e = se[1];
    float mx = -3.402823466e38f, sm = 0.f;
    int r = s;
    for (; r + 4 <= e; r += 4) {
        float v0 = bf2f(h3[(long)(r + 0) * 256 + t]);
        float v1 = bf2f(h3[(long)(r + 1) * 256 + t]);
        float v2 = bf2f(h3[(long)(r + 2) * 256 + t]);
        float v3 = bf2f(h3[(long)(r + 3) * 256 + t]);
        mx = fmaxf(mx, fmaxf(fmaxf(v0, v1), fmaxf(v2, v3)));
        sm += (v0 + v1) + (v2 + v3);
    }
    for (; r < e; ++r) {
        float v = bf2f(h3[(long)r * 256 + t]);
        mx = fmaxf(mx, v); sm += v;
    }
    float cnt = fmaxf((float)(e - s), 1.f);
    float av = sm / cnt;
    // final: out[g][c] = sum_t (mx_t*W3[t][c] + av_t*W3[256+t][c]) + b3[c]
    for (int c = 0; c < C; ++c) {
        float part = mx * W3[(long)t * C + c] + av * W3[(long)(256 + t) * C + c];
        part = wave_sum_dpp(part);       // uniform per wave
        if ((t & 63) == 0) wpart[t >> 6] = part;
        __syncthreads();
        if (t == 0)
            out[g * C + c] = wpart[0] + wpart[1] + wpart[2] + wpart[3] + b3[c];
        __syncthreads();
    }
}

// ---------------------------------------------------------------------------
extern "C" void kernel_launch(void* const* d_in, const int* in_sizes, int n_in,
                              void* d_out, int out_size, void* d_ws, size_t ws_size,
                              hipStream_t stream) {
    const float* x     = (const float*)d_in[0];
    const int*   ei    = (const int*)d_in[1];
    const int*   batch = (const int*)d_in[2];
    const float* W1    = (const float*)d_in[3];
    const float* b1    = (const float*)d_in[4];
    const float* beta2 = (const float*)d_in[5];
    const float* W2    = (const float*)d_in[6];
    const float* b2    = (const float*)d_in[7];
    const float* W3    = (const float*)d_in[8];
    const float* b3    = (const float*)d_in[9];
    float* out = (float*)d_out;

    const int N = in_sizes[2];          // 30000
    const int E = in_sizes[1] / 2;      // 480000
    const int F_IN = in_sizes[0] / N;   // 1280
    const int H = in_sizes[4];          // 512
    const int H2 = in_sizes[7];         // 256
    const int C = in_sizes[9];          // 10
    const int G = out_size / C;         // 64

    char* ws = (char*)d_ws;
    unsigned short* H1B = (unsigned short*)(ws + 0);            // 30.72 MB bf16
    unsigned short* H3B = (unsigned short*)(ws + 0);            // 15.36 MB bf16 (over H1B, dead)
    unsigned short* HPB = (unsigned short*)(ws + 31000000L);    // 30.72 MB bf16
    unsigned short* H2B = (unsigned short*)(ws + 62000000L);    // 30.72 MB bf16
    unsigned short* W1T = (unsigned short*)(ws + 93000000L);    // 1.31 MB
    unsigned short* W2T = (unsigned short*)(ws + 94500000L);    // 0.26 MB
    float* INVN_A = (float*)(ws + 95000000L);                   // 120 KB
    float* INVN_B = (float*)(ws + 95200000L);                   // 120 KB
    int*   CNT    = (int*)(ws + 95400000L);                     // 120 KB (memset 0)
    int*   FILL   = (int*)(ws + 95600000L);                     // 120 KB (memset 0)
    int*   ROWP   = (int*)(ws + 95800000L);
    int*   COL    = (int*)(ws + 96000000L);                     // 2.04 MB
    int*   BSUM   = (int*)(ws + 98100000L);                     // 256 B
    float* PSUM   = (float*)(ws + 98110000L);                   // <= 1.92 MB

    // 0. zero CNT + FILL in one async memset (covers 95.4M .. 95.8M)
    hipMemsetAsync(ws + 95400000L, 0, 400000, stream);

    // 1. weight transposes (f32 -> bf16 [N][K]) — single launch
    int nt1 = (F_IN / 32) * (H / 32);                // 640
    int nt2 = (H / 32) * (H2 / 32);                  // 128
    k_transpose_both<<<nt1 + nt2, 256, 0, stream>>>(W1, W1T, F_IN, H, nt1,
                                                    W2, W2T, H, H2);

    // 2. CSR (incoming edges; self loop folded into scan1's +1)
    int nb = (N + 1023) / 1024;   // 30
    k_csr_count<<<(E + 255) / 256, 256, 0, stream>>>(ei, CNT, E);
    k_scan1<<<nb, 1024, 0, stream>>>(CNT, ROWP, BSUM, N);
    k_scan23<<<(N + 1 + 1023) / 1024, 1024, 0, stream>>>(BSUM, ROWP, N, nb);
    k_csr_fill<<<(E + N + 255) / 256, 256, 0, stream>>>(ei, ROWP, FILL, COL, E, N);

    int nmt = (N + 255) / 256;                       // 118 m-tiles

    // 3. GEMM1: H1B = bf16(relu(x @ W1 + b1)) [N,512]; 256x256 tiles,
    //    epilogue emits per-row sumsq partials -> PSUM (SLOTS=8)
    {
        dim3 grid(nmt, H / 256);
        k_gemm_bias_relu<256, 1280, 256, 512, true, true, true>
            <<<grid, 512, 0, stream>>>(x, W1T, b1, H1B, PSUM, N);
    }
    k_rsqrt<8><<<(N + 255) / 256, 256, 0, stream>>>(PSUM, INVN_A, N);

    // 4. prop1 (beta=1): HPB = AGNN(H1B), fused invn of HPB -> INVN_B
    k_agnn<<<(N + 3) / 4, 256, 0, stream>>>(H1B, INVN_A, ROWP, COL, nullptr, HPB, INVN_B, N);

    // 5. prop2 (beta=beta2): H2B = AGNN(HPB)
    k_agnn<<<(N + 3) / 4, 256, 0, stream>>>(HPB, INVN_B, ROWP, COL, beta2, H2B, nullptr, N);

    // 6. GEMM2: H3B = bf16(relu(H2B @ W2 + b2)) [N,256]; 256x256 tiles
    {
        dim3 grid(nmt, 1);
        k_gemm_bias_relu<256, 512, 256, 256, false, true, false>
            <<<grid, 512, 0, stream>>>(H2B, W2T, b2, H3B, nullptr, N);
    }

    // 7. fused pool + final linear
    k_pool_final<<<G, 256, 0, stream>>>(H3B, batch, W3, b3, out, N, C);
}

// Round 16
// 340.840 us; speedup vs baseline: 1.0770x; 1.0770x over previous
//
#include <hip/hip_runtime.h>
#include <hip/hip_bf16.h>
#include <cstdint>

// ---------------------------------------------------------------------------
// Model: h=relu(x@W1+b1); h=AGNN(h,beta=1); h=AGNN(h,beta2); h=relu(h@W2+b2);
//        out = concat(segmax(h,batch), segmean(h,batch)) @ W3 + b3
// N=30000, E=480000, F_IN=1280, H=512, H2=256, G=64, C=10
// bf16 rows after GEMM1; r13-proven 8-wave 2-phase MFMA GEMM
// (GEMM1 128x256 fetch-once-A, GEMM2 128x128). GEMM1 epilogue emits per-row
// sumsq partials (replaces k_norm); XOR-swizzled LDS; AGNN fixed-shift
// softmax + 2-edge ILP + packed v_pk_fma_f32 math + DPP reduce; CSR via
// memset + scan-fold, edge-count merged into transpose launch; fused
// pool+final. 11 launches total.
// ---------------------------------------------------------------------------

typedef __attribute__((ext_vector_type(8))) short bf16x8;
typedef __attribute__((ext_vector_type(2))) float f32x2;
typedef __attribute__((ext_vector_type(4))) float f32x4;
typedef __attribute__((ext_vector_type(8))) unsigned short ushort8;
typedef __attribute__((ext_vector_type(4))) unsigned short ushort4v;
typedef __attribute__((ext_vector_type(4))) unsigned int uint4v;

__device__ inline unsigned short f2bf(float f) {
    unsigned int u = __float_as_uint(f);
    u += 0x7FFFu + ((u >> 16) & 1u);   // RNE
    return (unsigned short)(u >> 16);
}

__device__ __forceinline__ float bf2f(unsigned short u) {
    return __uint_as_float(((unsigned int)u) << 16);
}

// packed f32x2 -> bf16x2 (RNE), single HW instruction on gfx950
__device__ __forceinline__ unsigned int cvtpk(float lo, float hi) {
    unsigned int r;
    asm("v_cvt_pk_bf16_f32 %0, %1, %2" : "=v"(r) : "v"(lo), "v"(hi));
    return r;
}

__device__ __forceinline__ void gload_lds16(const void* g, void* l) {
    __builtin_amdgcn_global_load_lds(
        (const __attribute__((address_space(1))) void*)g,
        (__attribute__((address_space(3))) void*)l, 16, 0, 0);
}

// ---- wave64 sum via DPP (VALU pipe). Result uniform across the wave. ------
__device__ __forceinline__ float wave_sum_dpp(float p) {
    int t;
    t = __builtin_amdgcn_update_dpp(0, __float_as_int(p), 0xB1, 0xf, 0xf, true);  // quad_perm [1,0,3,2]
    p += __int_as_float(t);
    t = __builtin_amdgcn_update_dpp(0, __float_as_int(p), 0x4E, 0xf, 0xf, true);  // quad_perm [2,3,0,1]
    p += __int_as_float(t);
    t = __builtin_amdgcn_update_dpp(0, __float_as_int(p), 0x141, 0xf, 0xf, true); // row_half_mirror
    p += __int_as_float(t);
    t = __builtin_amdgcn_update_dpp(0, __float_as_int(p), 0x140, 0xf, 0xf, true); // row_mirror
    p += __int_as_float(t);
    t = __builtin_amdgcn_update_dpp(0, __float_as_int(p), 0x142, 0xf, 0xf, true); // row_bcast15
    p += __int_as_float(t);
    t = __builtin_amdgcn_update_dpp(0, __float_as_int(p), 0x143, 0xf, 0xf, true); // row_bcast31
    p += __int_as_float(t);
    return __int_as_float(__builtin_amdgcn_readlane(__float_as_int(p), 63));
}

// ---- sum across each 16-lane group (DPP row); all 16 lanes get the sum ----
__device__ __forceinline__ float row16_sum_dpp(float p) {
    int t;
    t = __builtin_amdgcn_update_dpp(0, __float_as_int(p), 0xB1, 0xf, 0xf, true);  // quad_perm xor1
    p += __int_as_float(t);
    t = __builtin_amdgcn_update_dpp(0, __float_as_int(p), 0x4E, 0xf, 0xf, true);  // quad_perm xor2
    p += __int_as_float(t);
    t = __builtin_amdgcn_update_dpp(0, __float_as_int(p), 0x141, 0xf, 0xf, true); // row_half_mirror
    p += __int_as_float(t);
    t = __builtin_amdgcn_update_dpp(0, __float_as_int(p), 0x140, 0xf, 0xf, true); // row_mirror
    p += __int_as_float(t);
    return p;
}

// ---- merged prep: both weight transposes + CSR edge count, one launch -----
__global__ __launch_bounds__(256) void k_prep(
    const float* __restrict__ W1, unsigned short* __restrict__ W1T,
    int K1, int N1, int nt1,
    const float* __restrict__ W2, unsigned short* __restrict__ W2T,
    int K2, int N2, int nt2,
    const int* __restrict__ ei, int* __restrict__ cnt, int E) {
    int id = blockIdx.x;
    if (id >= nt1 + nt2) {               // CSR edge count blocks
        int e = (id - nt1 - nt2) * 256 + threadIdx.x;
        if (e < E) atomicAdd(&cnt[ei[E + e]], 1);   // dst row
        return;
    }
    __shared__ unsigned short tb[32][33];
    const float* W; unsigned short* Wt; int K, N, bx, by;
    if (id < nt1) {
        W = W1; Wt = W1T; K = K1; N = N1;
        int nx = K1 / 32; bx = id % nx; by = id / nx;
    } else {
        id -= nt1;
        W = W2; Wt = W2T; K = K2; N = N2;
        int nx = K2 / 32; bx = id % nx; by = id / nx;
    }
    int k0 = bx * 32, n0 = by * 32;
    int tr = threadIdx.x >> 3;          // 0..31
    int tc = (threadIdx.x & 7) * 4;     // 0,4,...,28
    float4 v = *(const float4*)(W + (long)(k0 + tr) * N + n0 + tc);
    tb[tr][tc + 0] = f2bf(v.x); tb[tr][tc + 1] = f2bf(v.y);
    tb[tr][tc + 2] = f2bf(v.z); tb[tr][tc + 3] = f2bf(v.w);
    __syncthreads();
    ushort4v o = { tb[tc + 0][tr], tb[tc + 1][tr], tb[tc + 2][tr], tb[tc + 3][tr] };
    *(ushort4v*)(Wt + (long)(n0 + tr) * K + k0 + tc) = o;
}

// ---- MFMA GEMM: C[M][N] = relu(A[M][K] @ Bt[N][K]^T + bias) ---------------
// r13-proven schedule: block tile 128 x BN, 512 threads = 8 waves (2m x 4n),
// wave tile 64 x BN/4, BK=32, double-buffered LDS, ONE __syncthreads per
// K-step; next-tile loads issued before the MFMAs.
// PSUM_EN: epilogue reduces per-row sum of squares via 16-lane DPP groups;
// psum[row*SLOTS + blockIdx.y*4 + wn]; SLOTS = (NOUT/BN)*4.
// LDS rows 64B; 16B granule g of row r at slot g ^ ((r>>1)&3) (conflict-free,
// both sides). AF32: A f32 in global, reg-staged in-step + packed to bf16.
template <int K, int BN, int NOUT, bool AF32, bool OUTBF16, bool PSUM_EN>
__global__ __launch_bounds__(512, 4) void k_gemm_bias_relu(
    const void* __restrict__ Av, const unsigned short* __restrict__ Bt,
    const float* __restrict__ bias, void* __restrict__ Cv,
    float* __restrict__ psum, int M) {
    constexpr int NSTEP = K / 32;
    constexpr int NF = BN / 64;          // n-frags per wave
    constexpr int SLOTS = (NOUT / BN) * 4;
    __shared__ unsigned short As[2][128 * 32];
    __shared__ unsigned short Bs[2][BN * 32];
    int tid = threadIdx.x;
    int w = tid >> 6, l = tid & 63;
    int wm = w >> 2, wn = w & 3;
    int mBase = blockIdx.x * 128;
    int nBase = blockIdx.y * BN;

    const float* Af = (const float*)Av;
    const unsigned short* Ab = (const unsigned short*)Av;

    // AF32 reg-staging: thread owns 8 consecutive f32 of one row (4 thr/row)
    int arow = tid >> 2;                          // 0..127
    int aslot = (tid & 3) ^ ((arow >> 1) & 3);    // swizzled 16B slot
    long aRowG = mBase + arow; if (aRowG >= M) aRowG = M - 1;
    const float* aptr = AF32 ? (Af + aRowG * K + (tid & 3) * 8) : nullptr;

    auto stageB = [&](int b, int k0) {
#pragma unroll
        for (int o = 0; o < (BN + 127) / 128; ++o) {
            int rbase = (w * ((BN + 127) / 128) + o) * 16;   // wave-uniform
            int row = rbase + (l >> 2);                      // local B row
            int gsrc = (l & 3) ^ ((row >> 1) & 3);           // pre-swizzled src
            gload_lds16(Bt + (long)(nBase + row) * K + k0 + gsrc * 8,
                        &Bs[b][rbase * 32]);
        }
    };
    auto stageAbf = [&](int b, int k0) {
        int rbase = w * 16;
        int row = rbase + (l >> 2);
        int gsrc = (l & 3) ^ ((row >> 1) & 3);
        long gr = mBase + row; if (gr >= M) gr = M - 1;
        gload_lds16(Ab + gr * K + k0 + gsrc * 8, &As[b][rbase * 32]);
    };

    f32x4 acc[4][NF] = {};

    // ---- prologue: stage k-tile 0 into buffer 0 ---------------------------
    stageB(0, 0);
    if constexpr (AF32) {
        float4 z0 = *(const float4*)(aptr);
        float4 z1 = *(const float4*)(aptr + 4);
        uint4v p = { cvtpk(z0.x, z0.y), cvtpk(z0.z, z0.w),
                     cvtpk(z1.x, z1.y), cvtpk(z1.z, z1.w) };
        *(uint4v*)(&As[0][arow * 32 + aslot * 8]) = p;
    } else {
        stageAbf(0, 0);
    }
    __syncthreads();

    int s = 0;
    for (int step = 0; step < NSTEP; ++step, s ^= 1) {
        int nk = (step + 1) * 32;
        float4 f0, f1;
        if (nk < K) {                      // issue next-tile loads FIRST
            stageB(s ^ 1, nk);
            if constexpr (AF32) {
                f0 = *(const float4*)(aptr + nk);
                f1 = *(const float4*)(aptr + nk + 4);
            } else {
                stageAbf(s ^ 1, nk);
            }
        }
        // ---- compute current buffer (swizzled reads) ----------------------
        bf16x8 af[4];
#pragma unroll
        for (int m = 0; m < 4; ++m) {
            int ra = wm * 64 + m * 16 + (l & 15);
            int g = (l >> 4) ^ ((ra >> 1) & 3);
            af[m] = *(const bf16x8*)(&As[s][ra * 32 + g * 8]);
        }
#pragma unroll
        for (int n = 0; n < NF; ++n) {
            int rb = wn * (BN / 4) + n * 16 + (l & 15);
            int g = (l >> 4) ^ ((rb >> 1) & 3);
            bf16x8 bfr = *(const bf16x8*)(&Bs[s][rb * 32 + g * 8]);
#pragma unroll
            for (int m = 0; m < 4; ++m)
                acc[m][n] = __builtin_amdgcn_mfma_f32_16x16x32_bf16(
                    af[m], bfr, acc[m][n], 0, 0, 0);
        }
        if constexpr (AF32) {
            if (nk < K) {                    // write next A after MFMAs
                uint4v p = { cvtpk(f0.x, f0.y), cvtpk(f0.z, f0.w),
                             cvtpk(f1.x, f1.y), cvtpk(f1.z, f1.w) };
                *(uint4v*)(&As[s ^ 1][arow * 32 + aslot * 8]) = p;
            }
        }
        __syncthreads();
    }

    // ---- epilogue: row=(l>>4)*4+r, col=l&15 (HW-verified) -----------------
    float bv[NF];
#pragma unroll
    for (int n = 0; n < NF; ++n)
        bv[n] = bias[nBase + wn * (BN / 4) + n * 16 + (l & 15)];
#pragma unroll
    for (int m = 0; m < 4; ++m) {
#pragma unroll
        for (int r = 0; r < 4; ++r) {
            int row = mBase + wm * 64 + m * 16 + (l >> 4) * 4 + r;
            float sq = 0.f;
#pragma unroll
            for (int n = 0; n < NF; ++n) {
                float v = fmaxf(acc[m][n][r] + bv[n], 0.f);
                sq += v * v;
                if (row < M) {
                    int colg = nBase + wn * (BN / 4) + n * 16 + (l & 15);
                    if constexpr (OUTBF16)
                        ((unsigned short*)Cv)[(long)row * NOUT + colg] = f2bf(v);
                    else
                        ((float*)Cv)[(long)row * NOUT + colg] = v;
                }
            }
            if constexpr (PSUM_EN) {
                sq = row16_sum_dpp(sq);      // sum over this wave's cols
                if ((l & 15) == 0 && row < M)
                    psum[(long)row * SLOTS + blockIdx.y * 4 + wn] = sq;
            }
        }
    }
}

// ---- finish: invn[i] = rsqrt(sum of SLOTS psum entries) -------------------
template <int SLOTS>
__global__ void k_rsqrt(const float* __restrict__ psum,
                        float* __restrict__ invn, int n) {
    int i = blockIdx.x * 256 + threadIdx.x;
    if (i >= n) return;
    const float* p = psum + (long)i * SLOTS;
    float s = 0.f;
#pragma unroll
    for (int j = 0; j < SLOTS; j += 4) {
        float4 a = *(const float4*)(p + j);
        s += (a.x + a.y) + (a.z + a.w);
    }
    invn[i] = 1.f / fmaxf(sqrtf(s), 1e-12f);
}

// phase 1: per-1024-chunk exclusive scan of (cnt[i]+1) + chunk totals.
// The +1 is the self-loop (replaces a separate init kernel).
__global__ __launch_bounds__(1024) void k_scan1(const int* __restrict__ cnt,
                                                int* __restrict__ rowp,
                                                int* __restrict__ bsum, int n) {
    __shared__ int wsum[16];
    int b = blockIdx.x, t = threadIdx.x, lane = t & 63, w = t >> 6;
    int i = b * 1024 + t;
    int v = (i < n) ? cnt[i] + 1 : 0;
    int x = v;
#pragma unroll
    for (int off = 1; off < 64; off <<= 1) {
        int y = __shfl_up(x, off, 64);
        if (lane >= off) x += y;
    }
    if (lane == 63) wsum[w] = x;
    __syncthreads();
    if (t < 16) {
        int s = wsum[t];
#pragma unroll
        for (int off = 1; off < 16; off <<= 1) {
            int y = __shfl_up(s, off, 64);
            if (t >= off) s += y;
        }
        wsum[t] = s;
    }
    __syncthreads();
    int wo = w ? wsum[w - 1] : 0;
    if (i < n) rowp[i] = wo + x - v;            // chunk-local exclusive
    if (t == 0) bsum[b] = wsum[15];             // chunk total
}

// phase 2+3 fused: every block redundantly wave-scans the <=64 chunk totals,
// then adds its chunk offset; rowp[n] = grand total.
__global__ __launch_bounds__(1024) void k_scan23(const int* __restrict__ bsum,
                                                 int* __restrict__ rowp, int n, int nb) {
    __shared__ int off[65];
    int t = threadIdx.x;
    if (t < 64) {
        int v = (t < nb) ? bsum[t] : 0;
        int x = v;
#pragma unroll
        for (int o = 1; o < 64; o <<= 1) {
            int y = __shfl_up(x, o, 64);
            if (t >= o) x += y;
        }
        off[t] = x - v;                    // exclusive
        if (t == nb - 1) off[64] = x;      // total
    }
    __syncthreads();
    int i = blockIdx.x * 1024 + t;
    if (i < n) rowp[i] += off[i >> 10];
    else if (i == n) rowp[n] = off[64];
}

__global__ void k_csr_fill(const int* __restrict__ ei, const int* __restrict__ rowp,
                           int* __restrict__ fill, int* __restrict__ col, int E, int n) {
    int idx = blockIdx.x * blockDim.x + threadIdx.x;
    if (idx < E) {
        int d = ei[E + idx];
        int s = ei[idx];
        int pos = atomicAdd(&fill[d], 1);
        col[rowp[d] + pos] = s;
    } else if (idx < E + n) {
        int nd = idx - E;
        int pos = atomicAdd(&fill[nd], 1);
        col[rowp[nd] + pos] = nd;   // self loop
    }
}

// ---- AGNN propagation: bf16 rows, one wave per dst, single-pass -----------
// Fixed-shift softmax: alpha = beta*cos(theta) bounded by |beta|*(1+eps), so
// exp(alpha - 1.0625|beta|) never overflows; shift invariance => exact.
// 2-edge interleave + 4-deep row prefetch + DPP reduce.
// Dot & accumulate in f32x2 vectors -> clang emits v_pk_fma_f32 (VOP3P,
// 2 lanes/instr) cutting the per-edge VALU chain ~35%.
__global__ __launch_bounds__(256) void k_agnn(
    const unsigned short* __restrict__ h, const float* __restrict__ invn,
    const int* __restrict__ rowp, const int* __restrict__ col,
    const float* __restrict__ beta_ptr, unsigned short* __restrict__ out,
    float* __restrict__ invn_out, int nNodes) {
    int dst = blockIdx.x * 4 + (threadIdx.x >> 6);
    int lane = threadIdx.x & 63;
    if (dst >= nNodes) return;
    float beta = beta_ptr ? beta_ptr[0] : 1.0f;
    ushort8 hdv = *(const ushort8*)(h + (long)dst * 512 + lane * 8);
    f32x2 hd2[4];
#pragma unroll
    for (int k = 0; k < 4; ++k) {
        f32x2 t = { bf2f(hdv[2 * k]), bf2f(hdv[2 * k + 1]) };
        hd2[k] = t;
    }
    float coef = beta * invn[dst];
    float mshift = fabsf(beta) * 1.0625f;   // >= max possible alpha
    int s0 = rowp[dst], s1 = rowp[dst + 1];

    float ssum = 0.f;
    f32x2 accE[4] = {}, accO[4] = {};

    for (int base = s0; base < s1; base += 64) {
        int cnt = min(s1 - base, 64);
        int gi = base + lane; if (gi >= s1) gi = s1 - 1;
        int idxl = col[gi];              // batch of up to 64 edge indices
        float vinl = invn[idxl];         // batch of src inv-norms
        ushort8 r0 = {}, r1 = {}, r2 = {}, r3 = {};
        r0 = *(const ushort8*)(h + (long)__builtin_amdgcn_readlane(idxl, 0) * 512 + lane * 8);
        if (cnt > 1) r1 = *(const ushort8*)(h + (long)__builtin_amdgcn_readlane(idxl, 1) * 512 + lane * 8);
        if (cnt > 2) r2 = *(const ushort8*)(h + (long)__builtin_amdgcn_readlane(idxl, 2) * 512 + lane * 8);
        if (cnt > 3) r3 = *(const ushort8*)(h + (long)__builtin_amdgcn_readlane(idxl, 3) * 512 + lane * 8);
        int j = 0;
        for (; j + 1 < cnt; j += 2) {
            ushort8 c0 = r0, c1 = r1;
            r0 = r2; r1 = r3;
            if (j + 4 < cnt) r2 = *(const ushort8*)(h + (long)__builtin_amdgcn_readlane(idxl, j + 4) * 512 + lane * 8);
            if (j + 5 < cnt) r3 = *(const ushort8*)(h + (long)__builtin_amdgcn_readlane(idxl, j + 5) * 512 + lane * 8);
            f32x2 a0[4], a1[4];
#pragma unroll
            for (int k = 0; k < 4; ++k) {
                f32x2 t0 = { bf2f(c0[2 * k]), bf2f(c0[2 * k + 1]) };
                f32x2 t1 = { bf2f(c1[2 * k]), bf2f(c1[2 * k + 1]) };
                a0[k] = t0; a1[k] = t1;
            }
            f32x2 q0 = a0[0] * hd2[0] + a0[1] * hd2[1] +
                       a0[2] * hd2[2] + a0[3] * hd2[3];
            f32x2 q1 = a1[0] * hd2[0] + a1[1] * hd2[1] +
                       a1[2] * hd2[2] + a1[3] * hd2[3];
            float p0 = q0[0] + q0[1];
            float p1 = q1[0] + q1[1];
            p0 = wave_sum_dpp(p0);       // two independent chains interleave
            p1 = wave_sum_dpp(p1);
            float al0 = coef * __int_as_float(__builtin_amdgcn_readlane(__float_as_int(vinl), j)) * p0;
            float al1 = coef * __int_as_float(__builtin_amdgcn_readlane(__float_as_int(vinl), j + 1)) * p1;
            float w0 = __expf(al0 - mshift);
            float w1 = __expf(al1 - mshift);
            ssum += w0 + w1;
            f32x2 w02 = { w0, w0 }, w12 = { w1, w1 };
#pragma unroll
            for (int k = 0; k < 4; ++k) {
                accE[k] += w02 * a0[k];
                accO[k] += w12 * a1[k];
            }
        }
        if (j < cnt) {                   // odd tail
            f32x2 a0[4];
#pragma unroll
            for (int k = 0; k < 4; ++k) {
                f32x2 t0 = { bf2f(r0[2 * k]), bf2f(r0[2 * k + 1]) };
                a0[k] = t0;
            }
            f32x2 q0 = a0[0] * hd2[0] + a0[1] * hd2[1] +
                       a0[2] * hd2[2] + a0[3] * hd2[3];
            float p0 = q0[0] + q0[1];
            p0 = wave_sum_dpp(p0);
            float al0 = coef * __int_as_float(__builtin_amdgcn_readlane(__float_as_int(vinl), j)) * p0;
            float w0 = __expf(al0 - mshift);
            ssum += w0;
            f32x2 w02 = { w0, w0 };
#pragma unroll
            for (int k = 0; k < 4; ++k) accE[k] += w02 * a0[k];
        }
    }
    float inv_s = 1.f / ssum;
    f32x2 inv2 = { inv_s, inv_s };
    f32x2 acc2[4];
#pragma unroll
    for (int k = 0; k < 4; ++k) acc2[k] = (accE[k] + accO[k]) * inv2;

    uint4v o = { cvtpk(acc2[0][0], acc2[0][1]), cvtpk(acc2[1][0], acc2[1][1]),
                 cvtpk(acc2[2][0], acc2[2][1]), cvtpk(acc2[3][0], acc2[3][1]) };
    *(uint4v*)(out + (long)dst * 512 + lane * 8) = o;

    if (invn_out) {                      // fused output norm (feeds next prop)
        float s = 0.f;
#pragma unroll
        for (int k = 0; k < 4; ++k)
            s += acc2[k][0] * acc2[k][0] + acc2[k][1] * acc2[k][1];
        s = wave_sum_dpp(s);
        if (lane == 0) invn_out[dst] = 1.f / fmaxf(sqrtf(s), 1e-12f);
    }
}

// ---- fused per-graph pool (max/mean, bf16 in) + final linear --------------
__global__ __launch_bounds__(256) void k_pool_final(
    const unsigned short* __restrict__ h3, const int* __restrict__ batch,
    const float* __restrict__ W3, const float* __restrict__ b3,
    float* __restrict__ out, int n, int C) {
    __shared__ int se[2];
    __shared__ float wpart[4];
    int g = blockIdx.x;
    int t = threadIdx.x;
    if (t < 2) {                         // binary search graph boundaries
        int tgt = g + t;
        int lo = 0, hi = n;
        while (lo < hi) {
            int mid = (lo + hi) >> 1;
            if (batch[mid] < tgt) lo = mid + 1; else hi = mid;
        }
        se[t] = lo;
    }
    __syncthreads();
    int s = se[0], e = se[1];
    float mx = -3.402823466e38f, sm = 0.f;
    int r = s;
    for (; r + 4 <= e; r += 4) {
        float v0 = bf2f(h3[(long)(r + 0) * 256 + t]);
        float v1 = bf2f(h3[(long)(r + 1) * 256 + t]);
        float v2 = bf2f(h3[(long)(r + 2) * 256 + t]);
        float v3 = bf2f(h3[(long)(r + 3) * 256 + t]);
        mx = fmaxf(mx, fmaxf(fmaxf(v0, v1), fmaxf(v2, v3)));
        sm += (v0 + v1) + (v2 + v3);
    }
    for (; r < e; ++r) {
        float v = bf2f(h3[(long)r * 256 + t]);
        mx = fmaxf(mx, v); sm += v;
    }
    float cnt = fmaxf((float)(e - s), 1.f);
    float av = sm / cnt;
    // final: out[g][c] = sum_t (mx_t*W3[t][c] + av_t*W3[256+t][c]) + b3[c]
    for (int c = 0; c < C; ++c) {
        float part = mx * W3[(long)t * C + c] + av * W3[(long)(256 + t) * C + c];
        part = wave_sum_dpp(part);       // uniform per wave
        if ((t & 63) == 0) wpart[t >> 6] = part;
        __syncthreads();
        if (t == 0)
            out[g * C + c] = wpart[0] + wpart[1] + wpart[2] + wpart[3] + b3[c];
        __syncthreads();
    }
}

// ---------------------------------------------------------------------------
extern "C" void kernel_launch(void* const* d_in, const int* in_sizes, int n_in,
                              void* d_out, int out_size, void* d_ws, size_t ws_size,
                              hipStream_t stream) {
    const float* x     = (const float*)d_in[0];
    const int*   ei    = (const int*)d_in[1];
    const int*   batch = (const int*)d_in[2];
    const float* W1    = (const float*)d_in[3];
    const float* b1    = (const float*)d_in[4];
    const float* beta2 = (const float*)d_in[5];
    const float* W2    = (const float*)d_in[6];
    const float* b2    = (const float*)d_in[7];
    const float* W3    = (const float*)d_in[8];
    const float* b3    = (const float*)d_in[9];
    float* out = (float*)d_out;

    const int N = in_sizes[2];          // 30000
    const int E = in_sizes[1] / 2;      // 480000
    const int F_IN = in_sizes[0] / N;   // 1280
    const int H = in_sizes[4];          // 512
    const int H2 = in_sizes[7];         // 256
    const int C = in_sizes[9];          // 10
    const int G = out_size / C;         // 64

    char* ws = (char*)d_ws;
    unsigned short* H1B = (unsigned short*)(ws + 0);            // 30.72 MB bf16
    unsigned short* H3B = (unsigned short*)(ws + 0);            // 15.36 MB bf16 (over H1B, dead)
    unsigned short* HPB = (unsigned short*)(ws + 31000000L);    // 30.72 MB bf16
    unsigned short* H2B = (unsigned short*)(ws + 62000000L);    // 30.72 MB bf16
    unsigned short* W1T = (unsigned short*)(ws + 93000000L);    // 1.31 MB
    unsigned short* W2T = (unsigned short*)(ws + 94500000L);    // 0.26 MB
    float* INVN_A = (float*)(ws + 95000000L);                   // 120 KB
    float* INVN_B = (float*)(ws + 95200000L);                   // 120 KB
    int*   CNT    = (int*)(ws + 95400000L);                     // 120 KB (memset 0)
    int*   FILL   = (int*)(ws + 95600000L);                     // 120 KB (memset 0)
    int*   ROWP   = (int*)(ws + 95800000L);
    int*   COL    = (int*)(ws + 96000000L);                     // 2.04 MB
    int*   BSUM   = (int*)(ws + 98100000L);                     // 256 B
    float* PSUM   = (float*)(ws + 98110000L);                   // <= 1.92 MB

    // 0. zero CNT + FILL in one async memset (covers 95.4M .. 95.8M)
    hipMemsetAsync(ws + 95400000L, 0, 400000, stream);

    // 1. prep: both weight transposes + CSR edge count (one launch)
    int nt1 = (F_IN / 32) * (H / 32);                // 640
    int nt2 = (H / 32) * (H2 / 32);                  // 128
    int ecb = (E + 255) / 256;                       // 1875
    k_prep<<<nt1 + nt2 + ecb, 256, 0, stream>>>(W1, W1T, F_IN, H, nt1,
                                                W2, W2T, H, H2, nt2,
                                                ei, CNT, E);

    // 2. CSR scan + fill (self loop folded into scan1's +1)
    int nb = (N + 1023) / 1024;   // 30
    k_scan1<<<nb, 1024, 0, stream>>>(CNT, ROWP, BSUM, N);
    k_scan23<<<(N + 1 + 1023) / 1024, 1024, 0, stream>>>(BSUM, ROWP, N, nb);
    k_csr_fill<<<(E + N + 255) / 256, 256, 0, stream>>>(ei, ROWP, FILL, COL, E, N);

    // 3. GEMM1: H1B = bf16(relu(x @ W1 + b1)) [N,512]; 128x256 tiles
    //    (A-f32 fetched once; epilogue emits per-row sumsq partials -> PSUM)
    {
        dim3 grid((N + 127) / 128, H / 256);
        k_gemm_bias_relu<1280, 256, 512, true, true, true>
            <<<grid, 512, 0, stream>>>(x, W1T, b1, H1B, PSUM, N);
    }
    k_rsqrt<8><<<(N + 255) / 256, 256, 0, stream>>>(PSUM, INVN_A, N);

    // 4. prop1 (beta=1): HPB = AGNN(H1B), fused invn of HPB -> INVN_B
    k_agnn<<<(N + 3) / 4, 256, 0, stream>>>(H1B, INVN_A, ROWP, COL, nullptr, HPB, INVN_B, N);

    // 5. prop2 (beta=beta2): H2B = AGNN(HPB)
    k_agnn<<<(N + 3) / 4, 256, 0, stream>>>(HPB, INVN_B, ROWP, COL, beta2, H2B, nullptr, N);

    // 6. GEMM2: H3B = bf16(relu(H2B @ W2 + b2)) [N,256]; 128x128 tiles
    {
        dim3 grid((N + 127) / 128, H2 / 128);
        k_gemm_bias_relu<512, 128, 256, false, true, false>
            <<<grid, 512, 0, stream>>>(H2B, W2T, b2, H3B, nullptr, N);
    }

    // 7. fused pool + final linear
    k_pool_final<<<G, 256, 0, stream>>>(H3B, batch, W3, b3, out, N, C);
}